// Round 16
// baseline (35.430 us; speedup 1.0000x reference)
//
#include <hip/hip_runtime.h>
#include <hip/hip_bf16.h>

// InfoNCE-style loss: Xn=normalize(X), Yn=normalize(Y), logits=Xn@Yn^T/0.07,
// loss = mean_i(lse_i - logits[i,i]).
// Fixed-max trick: logits <= 1/T, so lse = 1/T + ln(sum exp(logit-1/T)).
// fp8 e4m3 inputs, MX-scaled mfma_scale_f32_16x16x128_f8f6f4, scale=1.0.
// R16: R15 champion with ONE change — all s_setprio removed from tile_step
// and prev-tile exps source-interleaved between MFMA pairs. Rationale:
// s_setprio is an LLVM scheduling-region boundary (unmodeled side effects),
// so the R9/R15 brackets FORBADE the compiler from hiding exp VALU under
// the MFMA issue stream; per-SIMD accounting shows ~50% stall from the
// resulting phase serialization (MFMA 32% + VALU 10% + LDS 15% busy).
// No SGB (R11 misfire), no fences, everything else byte-identical to R15.
//
// ws layout:
//   [0,2MB)        Xq fp8 [8192][256]
//   [2MB,4MB)      Yq fp8 [8192][256]
//   [4MB,+32KB)    diag f32[8192]
//   [4MB+32K,+32K) row_sum f32[8192]  (zeroed by nrm_kernel each call)

typedef __attribute__((ext_vector_type(2)))  float f32x2;
typedef __attribute__((ext_vector_type(4)))  float f32x4;
typedef __attribute__((ext_vector_type(4)))  int   i32x4;
typedef __attribute__((ext_vector_type(8)))  int   i32x8;

#define AS1(p) ((const __attribute__((address_space(1))) void*)(uintptr_t)(p))
#define AS3(p) ((__attribute__((address_space(3))) void*)(uintptr_t)(p))

constexpr int   BROWS = 8192;
constexpr int   DDIM  = 256;
constexpr float kInvT = 14.285714285714286f;   // 1/0.07
constexpr float kC1   = 20.609929155556622f;   // log2(e)/0.07
constexpr float kLn2  = 0.6931471805599453f;
constexpr int   kSC   = 0x7F7F7F7F;            // e8m0 scale bytes = 2^0 = 1.0

#if __has_builtin(__builtin_amdgcn_exp2f)
#define EXP2F(x) __builtin_amdgcn_exp2f(x)
#else
#define EXP2F(x) exp2f(x)
#endif
#if __has_builtin(__builtin_amdgcn_logf)
#define LOG2F(x) __builtin_amdgcn_logf(x)
#else
#define LOG2F(x) log2f(x)
#endif

// ---- f32 -> fp8 e4m3fn (RNE). Inputs here are |v| <= 1, finite. ----
static __device__ __forceinline__ unsigned f2fp8(float f) {
  unsigned u = __builtin_bit_cast(unsigned, f);
  unsigned s = (u >> 24) & 0x80u;
  float af = __builtin_fabsf(f);
  if (af < 0.015625f) {                    // below min normal 2^-6: denorm steps 2^-9
    int q = (int)__builtin_rintf(af * 512.0f);   // 0..8 (8 rolls into min normal)
    return s | (unsigned)q;
  }
  unsigned au = u & 0x7FFFFFFFu;
  au += 0x7FFFFu + ((au >> 20) & 1u);      // RNE on 3-bit mantissa
  unsigned e8 = ((au >> 23) - 127u + 7u) & 0xFu;
  unsigned m  = (au >> 20) & 7u;
  return s | (e8 << 3) | m;
}

// ---------------- normalize rows -> fp8, exact fp32 diagonal, zero row_sum --
__global__ __launch_bounds__(256) void nrm_kernel(
    const float* __restrict__ X, const float* __restrict__ Y,
    unsigned int* __restrict__ Xq, unsigned int* __restrict__ Yq,
    float* __restrict__ diag, float* __restrict__ row_sum)
{
  const int wave = threadIdx.x >> 6;
  const int lane = threadIdx.x & 63;
  const int row  = blockIdx.x * 4 + wave;
  const float4 x = *(const float4*)(X + (size_t)row * DDIM + lane * 4);
  const float4 y = *(const float4*)(Y + (size_t)row * DDIM + lane * 4);
  float ssx = x.x*x.x + x.y*x.y + x.z*x.z + x.w*x.w;
  float ssy = y.x*y.x + y.y*y.y + y.z*y.z + y.w*y.w;
  float dot = x.x*y.x + x.y*y.y + x.z*y.z + x.w*y.w;
  #pragma unroll
  for (int m = 1; m < 64; m <<= 1) {
    ssx += __shfl_xor(ssx, m);
    ssy += __shfl_xor(ssy, m);
    dot += __shfl_xor(dot, m);
  }
  const float invx = 1.0f / fmaxf(sqrtf(ssx), 1e-8f);
  const float invy = 1.0f / fmaxf(sqrtf(ssy), 1e-8f);
#if __has_builtin(__builtin_amdgcn_cvt_pk_fp8_f32)
  int xq = __builtin_amdgcn_cvt_pk_fp8_f32(x.x * invx, x.y * invx, 0, false);
  xq     = __builtin_amdgcn_cvt_pk_fp8_f32(x.z * invx, x.w * invx, xq, true);
  int yq = __builtin_amdgcn_cvt_pk_fp8_f32(y.x * invy, y.y * invy, 0, false);
  yq     = __builtin_amdgcn_cvt_pk_fp8_f32(y.z * invy, y.w * invy, yq, true);
#else
  int xq = (int)(f2fp8(x.x*invx) | (f2fp8(x.y*invx) << 8) |
                 (f2fp8(x.z*invx) << 16) | (f2fp8(x.w*invx) << 24));
  int yq = (int)(f2fp8(y.x*invy) | (f2fp8(y.y*invy) << 8) |
                 (f2fp8(y.z*invy) << 16) | (f2fp8(y.w*invy) << 24));
#endif
  Xq[row * 64 + lane] = (unsigned)xq;
  Yq[row * 64 + lane] = (unsigned)yq;
  if (lane == 0) {
    diag[row] = dot * invx * invy * kInvT;
    row_sum[row] = 0.0f;
  }
}

// ---- exp of one f32x4 slice of the PREVIOUS tile into sums ----
// (1 pk_fma x2 + 4 v_exp + 2 pk_add; independent of current-tile MFMAs)
static __device__ __forceinline__ void expq(const f32x4& pv, f32x2 (&sm)[2]) {
  f32x2 v0 = { pv[0], pv[1] };
  f32x2 v1 = { pv[2], pv[3] };
  v0 = v0 * kC1 + (f32x2){-kC1, -kC1};
  v1 = v1 * kC1 + (f32x2){-kC1, -kC1};
  sm[0] += (f32x2){ EXP2F(v0.x), EXP2F(v0.y) };
  sm[1] += (f32x2){ EXP2F(v1.x), EXP2F(v1.y) };
}

// -------- one B-tile (32 Y-rows x 256B fp8): 16 MX-MFMAs with the PREVIOUS
// tile's exps interleaved (T15 double-acc). NO setprio / SGB / fences: the
// whole tile is one scheduling region so the compiler hides exp VALU in the
// MFMA issue gaps. Reads: bb[n] ^ {0,16,128,144} (4-bit slot swizzle).
static __device__ __forceinline__ void tile_step(
    const char* __restrict__ tb, const int (&bb)[2], const i32x8 (&a)[4][2],
    f32x4 (&cur)[4][2], f32x4 (&prev)[4][2], f32x2 (&sums2)[4][2])
{
  const f32x4 cz = {0.f, 0.f, 0.f, 0.f};
  {  // ---- kb = 0: fresh C (no acc zeroing); flush prev[m][0] between pairs
    const i32x4 lo0 = *(const i32x4*)(tb + (bb[0]));
    const i32x4 hi0 = *(const i32x4*)(tb + (bb[0] ^ 16));
    const i32x4 lo1 = *(const i32x4*)(tb + (bb[1]));
    const i32x4 hi1 = *(const i32x4*)(tb + (bb[1] ^ 16));
    const i32x8 b0 = __builtin_shufflevector(lo0, hi0, 0, 1, 2, 3, 4, 5, 6, 7);
    const i32x8 b1 = __builtin_shufflevector(lo1, hi1, 0, 1, 2, 3, 4, 5, 6, 7);
    cur[0][0] = __builtin_amdgcn_mfma_scale_f32_16x16x128_f8f6f4(a[0][0], b0, cz, 0, 0, 0, kSC, 0, kSC);
    cur[0][1] = __builtin_amdgcn_mfma_scale_f32_16x16x128_f8f6f4(a[0][0], b1, cz, 0, 0, 0, kSC, 0, kSC);
    expq(prev[0][0], sums2[0]);
    cur[1][0] = __builtin_amdgcn_mfma_scale_f32_16x16x128_f8f6f4(a[1][0], b0, cz, 0, 0, 0, kSC, 0, kSC);
    cur[1][1] = __builtin_amdgcn_mfma_scale_f32_16x16x128_f8f6f4(a[1][0], b1, cz, 0, 0, 0, kSC, 0, kSC);
    expq(prev[1][0], sums2[1]);
    cur[2][0] = __builtin_amdgcn_mfma_scale_f32_16x16x128_f8f6f4(a[2][0], b0, cz, 0, 0, 0, kSC, 0, kSC);
    cur[2][1] = __builtin_amdgcn_mfma_scale_f32_16x16x128_f8f6f4(a[2][0], b1, cz, 0, 0, 0, kSC, 0, kSC);
    expq(prev[2][0], sums2[2]);
    cur[3][0] = __builtin_amdgcn_mfma_scale_f32_16x16x128_f8f6f4(a[3][0], b0, cz, 0, 0, 0, kSC, 0, kSC);
    cur[3][1] = __builtin_amdgcn_mfma_scale_f32_16x16x128_f8f6f4(a[3][0], b1, cz, 0, 0, 0, kSC, 0, kSC);
    expq(prev[3][0], sums2[3]);
  }
  {  // ---- kb = 1: accumulate; flush prev[m][1] between pairs
    const i32x4 lo0 = *(const i32x4*)(tb + (bb[0] ^ 128));
    const i32x4 hi0 = *(const i32x4*)(tb + (bb[0] ^ 144));
    const i32x4 lo1 = *(const i32x4*)(tb + (bb[1] ^ 128));
    const i32x4 hi1 = *(const i32x4*)(tb + (bb[1] ^ 144));
    const i32x8 b0 = __builtin_shufflevector(lo0, hi0, 0, 1, 2, 3, 4, 5, 6, 7);
    const i32x8 b1 = __builtin_shufflevector(lo1, hi1, 0, 1, 2, 3, 4, 5, 6, 7);
    cur[0][0] = __builtin_amdgcn_mfma_scale_f32_16x16x128_f8f6f4(a[0][1], b0, cur[0][0], 0, 0, 0, kSC, 0, kSC);
    cur[0][1] = __builtin_amdgcn_mfma_scale_f32_16x16x128_f8f6f4(a[0][1], b1, cur[0][1], 0, 0, 0, kSC, 0, kSC);
    expq(prev[0][1], sums2[0]);
    cur[1][0] = __builtin_amdgcn_mfma_scale_f32_16x16x128_f8f6f4(a[1][1], b0, cur[1][0], 0, 0, 0, kSC, 0, kSC);
    cur[1][1] = __builtin_amdgcn_mfma_scale_f32_16x16x128_f8f6f4(a[1][1], b1, cur[1][1], 0, 0, 0, kSC, 0, kSC);
    expq(prev[1][1], sums2[1]);
    cur[2][0] = __builtin_amdgcn_mfma_scale_f32_16x16x128_f8f6f4(a[2][1], b0, cur[2][0], 0, 0, 0, kSC, 0, kSC);
    cur[2][1] = __builtin_amdgcn_mfma_scale_f32_16x16x128_f8f6f4(a[2][1], b1, cur[2][1], 0, 0, 0, kSC, 0, kSC);
    expq(prev[2][1], sums2[2]);
    cur[3][0] = __builtin_amdgcn_mfma_scale_f32_16x16x128_f8f6f4(a[3][1], b0, cur[3][0], 0, 0, 0, kSC, 0, kSC);
    cur[3][1] = __builtin_amdgcn_mfma_scale_f32_16x16x128_f8f6f4(a[3][1], b1, cur[3][1], 0, 0, 0, kSC, 0, kSC);
    expq(prev[3][1], sums2[3]);
  }
}

// ---------------- main: exp-sum of logits over all columns ----------------
// 512 blocks x 256 thr (4 waves). Wave owns 64 X-rows = 4 m-frags of 16; A
// (fp8) in regs (64). Shared B tiles: 32 Y-rows x 256B (8KB), 4-deep ring
// (32KB LDS), all 4 waves co-stage (2 x 1KB global_load_lds each).
// LDS swizzle: byte (r,c) stored at r*256 + (((c>>4) ^ (r&15))<<4 | (c&15))
// -> every ds_read_b128 is 2 lanes/slot = conflict-free (0 measured).
// Schedule per tile t (counted-vmcnt, never drain in-loop):
//   s_waitcnt vmcnt(4); s_barrier; stage(t+3); tile_step(buf[t&3]).
// Epilogue waits: t=14 -> vmcnt(2), t=15 -> vmcnt(0).
__global__ __launch_bounds__(256, 2) void logits_kernel(
    const unsigned char* __restrict__ Xq,
    const unsigned char* __restrict__ Yq,
    float* __restrict__ row_sum)
{
  __shared__ char lds[4 * 8192];
  const int tid  = threadIdx.x;
  const int lane = tid & 63;
  const int wave = tid >> 6;
  const int l15  = lane & 15;
  const int g    = lane >> 4;      // 0..3: k-group / C-row group

  // XCD-aware bijective map: xcd=bid&7 owns 16 panels x 4 splits
  const int bid  = blockIdx.x;
  const int xcd  = bid & 7;
  const int idx  = bid >> 3;                        // 0..63
  const int panel = (xcd >> 2) * 16 + (idx & 15);   // 0..31
  const int split = (xcd & 3) * 4 + (idx >> 4);     // 0..15

  const int rowbase = panel * 256 + wave * 64;
  const char* Xb = (const char*)Xq;
  const char* Yb = (const char*)Yq + (size_t)split * (512 * 256);

  // A fragments (16x16x128 fp8): lane holds row (rowbase+16m+l15),
  // k-bytes [kb*128 + g*32, +32) -> i32x8 (32B, aligned).
  i32x8 a[4][2];
  #pragma unroll
  for (int m = 0; m < 4; ++m) {
    const char* rp = Xb + (size_t)(rowbase + m * 16 + l15) * 256 + g * 32;
    a[m][0] = *(const i32x8*)(rp);
    a[m][1] = *(const i32x8*)(rp + 128);
  }

  f32x2 sums2[4][2];
  #pragma unroll
  for (int m = 0; m < 4; ++m) {
    sums2[m][0] = (f32x2){0.f, 0.f};
    sums2[m][1] = (f32x2){0.f, 0.f};
  }

  // B read bases: row r = n*16+l15, slot s16 = kb*8 + 2g + h, swizzled
  // slot' = s16 ^ l15  ->  base (kb=0,h=0): r*256 + ((2g ^ l15)<<4);
  // other three reads are base ^ 16 (h), ^128 (kb), ^144 (both).
  int bb[2];
  #pragma unroll
  for (int n = 0; n < 2; ++n)
    bb[n] = (n * 16 + l15) * 256 + (((2 * g) ^ l15) << 4);

  // Co-staged: wave stages 2KB of the 8KB tile (2 x width-16 ops).
  auto stage = [&](int t, int buf) {
    const char* Yt = Yb + (size_t)t * 8192;
    char* db = lds + buf * 8192;
    #pragma unroll
    for (int s = 0; s < 2; ++s) {
      const int portion = (s * 4 + wave) * 1024;
      const int L = portion + lane * 16;
      const int src = (L & ~255) | ((L & 255) ^ (((L >> 8) & 15) << 4));
      __builtin_amdgcn_global_load_lds(AS1(Yt + src), AS3(db + portion), 16, 0, 0);
    }
  };

  // T15 double-acc: accA = cur of even tiles, accB = cur of odd tiles.
  // accB starts at -inf so tile 0's "prev" exp contributes exactly 0.
  f32x4 accA[4][2], accB[4][2];
  #pragma unroll
  for (int m = 0; m < 4; ++m)
    #pragma unroll
    for (int n = 0; n < 2; ++n) {
      accA[m][n] = (f32x4){0.f, 0.f, 0.f, 0.f};
      const float ni = -__builtin_inff();
      accB[m][n] = (f32x4){ni, ni, ni, ni};
    }

  stage(0, 0);
  stage(1, 1);
  stage(2, 2);
  #pragma unroll 1
  for (int p = 0; p < 8; ++p) {
    const int t = 2 * p;
    // even tile t
    if (p < 7) asm volatile("s_waitcnt vmcnt(4)" ::: "memory");
    else       asm volatile("s_waitcnt vmcnt(2)" ::: "memory");
    __builtin_amdgcn_s_barrier();
    if (t + 3 < 16) stage(t + 3, (t + 3) & 3);
    tile_step(lds + (t & 3) * 8192, bb, a, accA, accB, sums2);
    // odd tile t+1
    if (p < 7) asm volatile("s_waitcnt vmcnt(4)" ::: "memory");
    else       asm volatile("s_waitcnt vmcnt(0)" ::: "memory");
    __builtin_amdgcn_s_barrier();
    if (t + 4 < 16) stage(t + 4, (t + 4) & 3);
    tile_step(lds + ((t + 1) & 3) * 8192, bb, a, accB, accA, sums2);
  }
  // flush tile 15 (its results live in accB)
  #pragma unroll
  for (int m = 0; m < 4; ++m) {
    expq(accB[m][0], sums2[m]);
    expq(accB[m][1], sums2[m]);
  }

  // reduce across the 16 column-lanes; one atomic per row per split.
  // C/D mapping (16x16 family, R1-verified): col=l15, row = g*4 + reg.
  #pragma unroll
  for (int m = 0; m < 4; ++m)
    #pragma unroll
    for (int h = 0; h < 2; ++h)
      #pragma unroll
      for (int r2 = 0; r2 < 2; ++r2) {
        float s = (r2 == 0) ? sums2[m][h].x : sums2[m][h].y;
        s += __shfl_xor(s, 1);
        s += __shfl_xor(s, 2);
        s += __shfl_xor(s, 4);
        s += __shfl_xor(s, 8);
        if (l15 == 0)
          atomicAdd(row_sum + rowbase + m * 16 + g * 4 + h * 2 + r2, s);
      }
}

// ---------------- loss: single-kernel reduction (separate launch) ----------
__global__ __launch_bounds__(1024) void loss_kernel(
    const float* __restrict__ row_sum, const float* __restrict__ diag,
    float* __restrict__ out)
{
  const int t = threadIdx.x;
  double acc = 0.0;
  #pragma unroll
  for (int h = 0; h < 2; ++h) {
    const int i = h * 4096 + t * 4;
    const float4 s = *(const float4*)(row_sum + i);
    const float4 d = *(const float4*)(diag + i);
    acc += (double)(kInvT + LOG2F(s.x) * kLn2 - d.x);
    acc += (double)(kInvT + LOG2F(s.y) * kLn2 - d.y);
    acc += (double)(kInvT + LOG2F(s.z) * kLn2 - d.z);
    acc += (double)(kInvT + LOG2F(s.w) * kLn2 - d.w);
  }
  #pragma unroll
  for (int m = 1; m < 64; m <<= 1) acc += __shfl_xor(acc, m);
  __shared__ double red[16];
  if ((t & 63) == 0) red[t >> 6] = acc;
  __syncthreads();
  if (t == 0) {
    double tot = 0.0;
    #pragma unroll
    for (int w = 0; w < 16; ++w) tot += red[w];
    out[0] = (float)(tot / (double)BROWS);
  }
}

extern "C" void kernel_launch(void* const* d_in, const int* in_sizes, int n_in,
                              void* d_out, int out_size, void* d_ws, size_t ws_size,
                              hipStream_t stream) {
  (void)in_sizes; (void)n_in; (void)out_size; (void)ws_size;
  const float* X = (const float*)d_in[0];
  const float* Y = (const float*)d_in[1];
  char* w = (char*)d_ws;
  unsigned int* Xq = (unsigned int*)(w);
  unsigned int* Yq = (unsigned int*)(w + (2u << 20));
  float* diag    = (float*)(w + (4u << 20));
  float* row_sum = (float*)(w + (4u << 20) + (32u << 10));

  nrm_kernel<<<BROWS / 4, 256, 0, stream>>>(X, Y, Xq, Yq, diag, row_sum);
  logits_kernel<<<512, 256, 0, stream>>>((const unsigned char*)Xq,
                                         (const unsigned char*)Yq, row_sum);
  loss_kernel<<<1, 1024, 0, stream>>>(row_sum, diag, (float*)d_out);
}

// Round 17
// 35.136 us; speedup vs baseline: 1.0084x; 1.0084x over previous
//
#include <hip/hip_runtime.h>
#include <hip/hip_bf16.h>

// InfoNCE-style loss: Xn=normalize(X), Yn=normalize(Y), logits=Xn@Yn^T/0.07,
// loss = mean_i(lse_i - logits[i,i]).
// Fixed-max trick: logits <= 1/T, so lse = 1/T + ln(sum exp(logit-1/T)).
// fp8 e4m3 inputs, MX-scaled mfma_scale_f32_16x16x128_f8f6f4, scale=1.0.
// R17: champion + B-REGISTER PREFETCH (m201/T3 mechanism): barrier shifted
// one tile early (vmcnt(2) = "tile t+1 staged"), and tile t+1's kb0 LDS
// fragments are read into registers DURING tile t's MFMA/exp region, so no
// tile starts with an exposed lgkmcnt stall (the one m201-checklist item
// the 2-barrier champion lacked; 8 other structural variants were null).
//
// ws layout:
//   [0,2MB)        Xq fp8 [8192][256]
//   [2MB,4MB)      Yq fp8 [8192][256]
//   [4MB,+32KB)    diag f32[8192]
//   [4MB+32K,+32K) row_sum f32[8192]  (zeroed by nrm_kernel each call)

typedef __attribute__((ext_vector_type(2)))  float f32x2;
typedef __attribute__((ext_vector_type(4)))  float f32x4;
typedef __attribute__((ext_vector_type(4)))  int   i32x4;
typedef __attribute__((ext_vector_type(8)))  int   i32x8;

#define AS1(p) ((const __attribute__((address_space(1))) void*)(uintptr_t)(p))
#define AS3(p) ((__attribute__((address_space(3))) void*)(uintptr_t)(p))

constexpr int   BROWS = 8192;
constexpr int   DDIM  = 256;
constexpr float kInvT = 14.285714285714286f;   // 1/0.07
constexpr float kC1   = 20.609929155556622f;   // log2(e)/0.07
constexpr float kLn2  = 0.6931471805599453f;
constexpr int   kSC   = 0x7F7F7F7F;            // e8m0 scale bytes = 2^0 = 1.0

#if __has_builtin(__builtin_amdgcn_exp2f)
#define EXP2F(x) __builtin_amdgcn_exp2f(x)
#else
#define EXP2F(x) exp2f(x)
#endif
#if __has_builtin(__builtin_amdgcn_logf)
#define LOG2F(x) __builtin_amdgcn_logf(x)
#else
#define LOG2F(x) log2f(x)
#endif

#define MFMA __builtin_amdgcn_mfma_scale_f32_16x16x128_f8f6f4
#define SHUF(lo, hi) __builtin_shufflevector(lo, hi, 0, 1, 2, 3, 4, 5, 6, 7)

// ---- f32 -> fp8 e4m3fn (RNE). Inputs here are |v| <= 1, finite. ----
static __device__ __forceinline__ unsigned f2fp8(float f) {
  unsigned u = __builtin_bit_cast(unsigned, f);
  unsigned s = (u >> 24) & 0x80u;
  float af = __builtin_fabsf(f);
  if (af < 0.015625f) {
    int q = (int)__builtin_rintf(af * 512.0f);
    return s | (unsigned)q;
  }
  unsigned au = u & 0x7FFFFFFFu;
  au += 0x7FFFFu + ((au >> 20) & 1u);
  unsigned e8 = ((au >> 23) - 127u + 7u) & 0xFu;
  unsigned m  = (au >> 20) & 7u;
  return s | (e8 << 3) | m;
}

// ---------------- normalize rows -> fp8, exact fp32 diagonal, zero row_sum --
__global__ __launch_bounds__(256) void nrm_kernel(
    const float* __restrict__ X, const float* __restrict__ Y,
    unsigned int* __restrict__ Xq, unsigned int* __restrict__ Yq,
    float* __restrict__ diag, float* __restrict__ row_sum)
{
  const int wave = threadIdx.x >> 6;
  const int lane = threadIdx.x & 63;
  const int row  = blockIdx.x * 4 + wave;
  const float4 x = *(const float4*)(X + (size_t)row * DDIM + lane * 4);
  const float4 y = *(const float4*)(Y + (size_t)row * DDIM + lane * 4);
  float ssx = x.x*x.x + x.y*x.y + x.z*x.z + x.w*x.w;
  float ssy = y.x*y.x + y.y*y.y + y.z*y.z + y.w*y.w;
  float dot = x.x*y.x + x.y*y.y + x.z*y.z + x.w*y.w;
  #pragma unroll
  for (int m = 1; m < 64; m <<= 1) {
    ssx += __shfl_xor(ssx, m);
    ssy += __shfl_xor(ssy, m);
    dot += __shfl_xor(dot, m);
  }
  const float invx = 1.0f / fmaxf(sqrtf(ssx), 1e-8f);
  const float invy = 1.0f / fmaxf(sqrtf(ssy), 1e-8f);
#if __has_builtin(__builtin_amdgcn_cvt_pk_fp8_f32)
  int xq = __builtin_amdgcn_cvt_pk_fp8_f32(x.x * invx, x.y * invx, 0, false);
  xq     = __builtin_amdgcn_cvt_pk_fp8_f32(x.z * invx, x.w * invx, xq, true);
  int yq = __builtin_amdgcn_cvt_pk_fp8_f32(y.x * invy, y.y * invy, 0, false);
  yq     = __builtin_amdgcn_cvt_pk_fp8_f32(y.z * invy, y.w * invy, yq, true);
#else
  int xq = (int)(f2fp8(x.x*invx) | (f2fp8(x.y*invx) << 8) |
                 (f2fp8(x.z*invx) << 16) | (f2fp8(x.w*invx) << 24));
  int yq = (int)(f2fp8(y.x*invy) | (f2fp8(y.y*invy) << 8) |
                 (f2fp8(y.z*invy) << 16) | (f2fp8(y.w*invy) << 24));
#endif
  Xq[row * 64 + lane] = (unsigned)xq;
  Yq[row * 64 + lane] = (unsigned)yq;
  if (lane == 0) {
    diag[row] = dot * invx * invy * kInvT;
    row_sum[row] = 0.0f;
  }
}

// ---- exp of one f32x4 slice of the PREVIOUS tile into sums ----
static __device__ __forceinline__ void expq(const f32x4& pv, f32x2 (&sm)[2]) {
  f32x2 v0 = { pv[0], pv[1] };
  f32x2 v1 = { pv[2], pv[3] };
  v0 = v0 * kC1 + (f32x2){-kC1, -kC1};
  v1 = v1 * kC1 + (f32x2){-kC1, -kC1};
  sm[0] += (f32x2){ EXP2F(v0.x), EXP2F(v0.y) };
  sm[1] += (f32x2){ EXP2F(v1.x), EXP2F(v1.y) };
}

// -------- one tile: kb0 MFMAs run on PREFETCHED regs (bK0, zero LDS dep);
// kb1 frags read here (latency hidden under kb0 MFMAs + exps); next tile's
// kb0 frags prefetched into bN (consumed next iteration). T15 double-acc:
// prev tile's exps interleave throughout. One scheduling region (no
// setprio/SGB/fences) — compiler orders loads early, fills waits with exps.
static __device__ __forceinline__ void tile_compute(
    const char* __restrict__ tb_cur, const char* __restrict__ tb_next,
    bool doNext, const int (&bb)[2], const i32x8 (&a)[4][2],
    i32x8 (&bK0)[2], i32x8 (&bN)[2],
    f32x4 (&cur)[4][2], f32x4 (&prev)[4][2], f32x2 (&sums2)[4][2])
{
  const f32x4 cz = {0.f, 0.f, 0.f, 0.f};
  // kb1 fragment loads (current tile)
  const i32x4 lo0 = *(const i32x4*)(tb_cur + (bb[0] ^ 128));
  const i32x4 hi0 = *(const i32x4*)(tb_cur + (bb[0] ^ 144));
  const i32x4 lo1 = *(const i32x4*)(tb_cur + (bb[1] ^ 128));
  const i32x4 hi1 = *(const i32x4*)(tb_cur + (bb[1] ^ 144));
  // next-tile kb0 prefetch (tile t+1 is in LDS: this iter's barrier proved it)
  if (doNext) {
    const i32x4 nlo0 = *(const i32x4*)(tb_next + bb[0]);
    const i32x4 nhi0 = *(const i32x4*)(tb_next + (bb[0] ^ 16));
    const i32x4 nlo1 = *(const i32x4*)(tb_next + bb[1]);
    const i32x4 nhi1 = *(const i32x4*)(tb_next + (bb[1] ^ 16));
    bN[0] = SHUF(nlo0, nhi0);
    bN[1] = SHUF(nlo1, nhi1);
  }
  // kb0 MFMAs: operands already in registers -> no lgkm wait at tile start
  cur[0][0] = MFMA(a[0][0], bK0[0], cz, 0, 0, 0, kSC, 0, kSC);
  cur[0][1] = MFMA(a[0][0], bK0[1], cz, 0, 0, 0, kSC, 0, kSC);
  expq(prev[0][0], sums2[0]);
  cur[1][0] = MFMA(a[1][0], bK0[0], cz, 0, 0, 0, kSC, 0, kSC);
  cur[1][1] = MFMA(a[1][0], bK0[1], cz, 0, 0, 0, kSC, 0, kSC);
  expq(prev[1][0], sums2[1]);
  cur[2][0] = MFMA(a[2][0], bK0[0], cz, 0, 0, 0, kSC, 0, kSC);
  cur[2][1] = MFMA(a[2][0], bK0[1], cz, 0, 0, 0, kSC, 0, kSC);
  expq(prev[2][0], sums2[2]);
  cur[3][0] = MFMA(a[3][0], bK0[0], cz, 0, 0, 0, kSC, 0, kSC);
  cur[3][1] = MFMA(a[3][0], bK0[1], cz, 0, 0, 0, kSC, 0, kSC);
  expq(prev[3][0], sums2[3]);
  // kb1 MFMAs (loads above have had the whole kb0 cluster to land)
  const i32x8 b10 = SHUF(lo0, hi0);
  const i32x8 b11 = SHUF(lo1, hi1);
  cur[0][0] = MFMA(a[0][1], b10, cur[0][0], 0, 0, 0, kSC, 0, kSC);
  cur[0][1] = MFMA(a[0][1], b11, cur[0][1], 0, 0, 0, kSC, 0, kSC);
  expq(prev[0][1], sums2[0]);
  cur[1][0] = MFMA(a[1][1], b10, cur[1][0], 0, 0, 0, kSC, 0, kSC);
  cur[1][1] = MFMA(a[1][1], b11, cur[1][1], 0, 0, 0, kSC, 0, kSC);
  expq(prev[1][1], sums2[1]);
  cur[2][0] = MFMA(a[2][1], b10, cur[2][0], 0, 0, 0, kSC, 0, kSC);
  cur[2][1] = MFMA(a[2][1], b11, cur[2][1], 0, 0, 0, kSC, 0, kSC);
  expq(prev[2][1], sums2[2]);
  cur[3][0] = MFMA(a[3][1], b10, cur[3][0], 0, 0, 0, kSC, 0, kSC);
  cur[3][1] = MFMA(a[3][1], b11, cur[3][1], 0, 0, 0, kSC, 0, kSC);
  expq(prev[3][1], sums2[3]);
}

// ---------------- main: exp-sum of logits over all columns ----------------
// 512 blocks x 256 thr (4 waves). Wave owns 64 X-rows = 4 m-frags of 16; A
// (fp8) in regs (64). Shared B tiles: 32 Y-rows x 256B (8KB), 4-deep ring
// (32KB LDS), co-staged width-16 global_load_lds, 4-bit XOR slot swizzle
// (0 conflicts measured). NEW schedule per tile t (barrier one tile early):
//   vmcnt(2)   ; my 2 stage ops for tile t+1 retired (t+2 in flight)
//   s_barrier  ; all waves' portions of t+1 landed; buf[(t-1)&3] fully read
//   stage(t+3) ; overwrites buf[(t-1)&3]
//   compute(t) ; kb0 MFMAs on prefetched regs, read kb1(t) + kb0(t+1)
// Tail: p=7 uses vmcnt(0). Safety: reads of tile t-1 were lgkm-drained
// before each wave's previous-iteration MFMAs, hence before this barrier.
__global__ __launch_bounds__(256, 2) void logits_kernel(
    const unsigned char* __restrict__ Xq,
    const unsigned char* __restrict__ Yq,
    float* __restrict__ row_sum)
{
  __shared__ char lds[4 * 8192];
  const int tid  = threadIdx.x;
  const int lane = tid & 63;
  const int wave = tid >> 6;
  const int l15  = lane & 15;
  const int g    = lane >> 4;      // 0..3: k-group / C-row group

  // XCD-aware bijective map: xcd=bid&7 owns 16 panels x 4 splits
  const int bid  = blockIdx.x;
  const int xcd  = bid & 7;
  const int idx  = bid >> 3;                        // 0..63
  const int panel = (xcd >> 2) * 16 + (idx & 15);   // 0..31
  const int split = (xcd & 3) * 4 + (idx >> 4);     // 0..15

  const int rowbase = panel * 256 + wave * 64;
  const char* Xb = (const char*)Xq;
  const char* Yb = (const char*)Yq + (size_t)split * (512 * 256);

  // A fragments (16x16x128 fp8): lane holds row (rowbase+16m+l15),
  // k-bytes [kb*128 + g*32, +32) -> i32x8 (32B, aligned).
  i32x8 a[4][2];
  #pragma unroll
  for (int m = 0; m < 4; ++m) {
    const char* rp = Xb + (size_t)(rowbase + m * 16 + l15) * 256 + g * 32;
    a[m][0] = *(const i32x8*)(rp);
    a[m][1] = *(const i32x8*)(rp + 128);
  }

  f32x2 sums2[4][2];
  #pragma unroll
  for (int m = 0; m < 4; ++m) {
    sums2[m][0] = (f32x2){0.f, 0.f};
    sums2[m][1] = (f32x2){0.f, 0.f};
  }

  // B read bases: row r = n*16+l15, slot s16 = kb*8 + 2g + h, swizzled
  // slot' = s16 ^ l15 -> base (kb=0,h=0): r*256 + ((2g ^ l15)<<4);
  // other reads are base ^ 16 (h), ^128 (kb), ^144 (both).
  int bb[2];
  #pragma unroll
  for (int n = 0; n < 2; ++n)
    bb[n] = (n * 16 + l15) * 256 + (((2 * g) ^ l15) << 4);

  // Co-staged: wave stages 2KB of the 8KB tile (2 x width-16 ops).
  auto stage = [&](int t, int buf) {
    const char* Yt = Yb + (size_t)t * 8192;
    char* db = lds + buf * 8192;
    #pragma unroll
    for (int s = 0; s < 2; ++s) {
      const int portion = (s * 4 + wave) * 1024;
      const int L = portion + lane * 16;
      const int src = (L & ~255) | ((L & 255) ^ (((L >> 8) & 15) << 4));
      __builtin_amdgcn_global_load_lds(AS1(Yt + src), AS3(db + portion), 16, 0, 0);
    }
  };

  // T15 double-acc; accB starts at -inf so tile 0's "prev" exps contribute 0.
  f32x4 accA[4][2], accB[4][2];
  #pragma unroll
  for (int m = 0; m < 4; ++m)
    #pragma unroll
    for (int n = 0; n < 2; ++n) {
      accA[m][n] = (f32x4){0.f, 0.f, 0.f, 0.f};
      const float ni = -__builtin_inff();
      accB[m][n] = (f32x4){ni, ni, ni, ni};
    }

  // B kb0 double-buffer: bA = even tiles, bB = odd tiles (static names).
  i32x8 bA[2], bB[2];

  // Prologue: stage 3 tiles; wait tile 0 (outstanding tiles 1,2 = 4 ops);
  // barrier; prefetch tile 0's kb0 frags into bA.
  stage(0, 0);
  stage(1, 1);
  stage(2, 2);
  asm volatile("s_waitcnt vmcnt(4)" ::: "memory");
  __builtin_amdgcn_s_barrier();
  {
    const i32x4 plo0 = *(const i32x4*)(lds + bb[0]);
    const i32x4 phi0 = *(const i32x4*)(lds + (bb[0] ^ 16));
    const i32x4 plo1 = *(const i32x4*)(lds + bb[1]);
    const i32x4 phi1 = *(const i32x4*)(lds + (bb[1] ^ 16));
    bA[0] = SHUF(plo0, phi0);
    bA[1] = SHUF(plo1, phi1);
  }

  #pragma unroll 1
  for (int p = 0; p < 8; ++p) {
    const int t = 2 * p;
    // ---- even tile t (bufs: cur = t&3, next = (t+1)&3) ----
    if (p < 7) asm volatile("s_waitcnt vmcnt(2)" ::: "memory");
    else       asm volatile("s_waitcnt vmcnt(0)" ::: "memory");
    __builtin_amdgcn_s_barrier();
    if (t + 3 < 16) stage(t + 3, (t + 3) & 3);
    tile_compute(lds + (t & 3) * 8192, lds + ((t + 1) & 3) * 8192,
                 true, bb, a, bA, bB, accA, accB, sums2);
    // ---- odd tile t+1 ----
    if (p < 7) asm volatile("s_waitcnt vmcnt(2)" ::: "memory");
    else       asm volatile("s_waitcnt vmcnt(0)" ::: "memory");
    __builtin_amdgcn_s_barrier();
    if (t + 4 < 16) stage(t + 4, (t + 4) & 3);
    tile_compute(lds + ((t + 1) & 3) * 8192, lds + ((t + 2) & 3) * 8192,
                 (t + 2) < 16, bb, a, bB, bA, accB, accA, sums2);
  }
  // flush tile 15 (its results live in accB)
  #pragma unroll
  for (int m = 0; m < 4; ++m) {
    expq(accB[m][0], sums2[m]);
    expq(accB[m][1], sums2[m]);
  }

  // reduce across the 16 column-lanes; one atomic per row per split.
  // C/D mapping (16x16 family, R1-verified): col=l15, row = g*4 + reg.
  #pragma unroll
  for (int m = 0; m < 4; ++m)
    #pragma unroll
    for (int h = 0; h < 2; ++h)
      #pragma unroll
      for (int r2 = 0; r2 < 2; ++r2) {
        float s = (r2 == 0) ? sums2[m][h].x : sums2[m][h].y;
        s += __shfl_xor(s, 1);
        s += __shfl_xor(s, 2);
        s += __shfl_xor(s, 4);
        s += __shfl_xor(s, 8);
        if (l15 == 0)
          atomicAdd(row_sum + rowbase + m * 16 + g * 4 + h * 2 + r2, s);
      }
}

// ---------------- loss: single-kernel reduction (separate launch) ----------
__global__ __launch_bounds__(1024) void loss_kernel(
    const float* __restrict__ row_sum, const float* __restrict__ diag,
    float* __restrict__ out)
{
  const int t = threadIdx.x;
  double acc = 0.0;
  #pragma unroll
  for (int h = 0; h < 2; ++h) {
    const int i = h * 4096 + t * 4;
    const float4 s = *(const float4*)(row_sum + i);
    const float4 d = *(const float4*)(diag + i);
    acc += (double)(kInvT + LOG2F(s.x) * kLn2 - d.x);
    acc += (double)(kInvT + LOG2F(s.y) * kLn2 - d.y);
    acc += (double)(kInvT + LOG2F(s.z) * kLn2 - d.z);
    acc += (double)(kInvT + LOG2F(s.w) * kLn2 - d.w);
  }
  #pragma unroll
  for (int m = 1; m < 64; m <<= 1) acc += __shfl_xor(acc, m);
  __shared__ double red[16];
  if ((t & 63) == 0) red[t >> 6] = acc;
  __syncthreads();
  if (t == 0) {
    double tot = 0.0;
    #pragma unroll
    for (int w = 0; w < 16; ++w) tot += red[w];
    out[0] = (float)(tot / (double)BROWS);
  }
}

extern "C" void kernel_launch(void* const* d_in, const int* in_sizes, int n_in,
                              void* d_out, int out_size, void* d_ws, size_t ws_size,
                              hipStream_t stream) {
  (void)in_sizes; (void)n_in; (void)out_size; (void)ws_size;
  const float* X = (const float*)d_in[0];
  const float* Y = (const float*)d_in[1];
  char* w = (char*)d_ws;
  unsigned int* Xq = (unsigned int*)(w);
  unsigned int* Yq = (unsigned int*)(w + (2u << 20));
  float* diag    = (float*)(w + (4u << 20));
  float* row_sum = (float*)(w + (4u << 20) + (32u << 10));

  nrm_kernel<<<BROWS / 4, 256, 0, stream>>>(X, Y, Xq, Yq, diag, row_sum);
  logits_kernel<<<512, 256, 0, stream>>>((const unsigned char*)Xq,
                                         (const unsigned char*)Yq, row_sum);
  loss_kernel<<<1, 1024, 0, stream>>>(row_sum, diag, (float*)d_out);
}